// Round 1
// baseline (5154.084 us; speedup 1.0000x reference)
//
#include <hip/hip_runtime.h>
#include <hip/hip_bf16.h>

#define B_  256
#define T_  256
#define F_  64
#define U_  512
#define NG_ 2048   // 4*U

typedef __attribute__((ext_vector_type(8))) short short8;
typedef __attribute__((ext_vector_type(4))) float floatx4;

__device__ __forceinline__ unsigned short f2bf(float f) {
    union { float f; unsigned int u; } v; v.f = f;
    unsigned int u = v.u;
    unsigned int r = (u + 0x7FFFu + ((u >> 16) & 1u)) >> 16;
    return (unsigned short)r;
}

__device__ __forceinline__ float bf2f(unsigned short s) {
    union { unsigned int u; float f; } v; v.u = ((unsigned int)s) << 16;
    return v.f;
}

__global__ void cast_x_kernel(const float* __restrict__ x,
                              unsigned short* __restrict__ xb, int n) {
    int i = blockIdx.x * blockDim.x + threadIdx.x;
    if (i < n) xb[i] = f2bf(x[i]);
}

// Pack [W (KTx ktiles of K=32); U (KT-KTx ktiles)] columns into MFMA-B frag
// order: dst[((ntile*KT + kt)*64 + lane)*8 + j] = M[k = kt*32 + (lane>>4)*8 + j]
//                                                  [n = ntile*16 + (lane&15)]
__global__ void pack_kernel(const float* __restrict__ W, const float* __restrict__ Uw,
                            unsigned short* __restrict__ dst, int KT, int KTx) {
    long tid = (long)blockIdx.x * blockDim.x + threadIdx.x;
    long total = (long)128 * KT * 512;
    if (tid >= total) return;
    int j      = (int)(tid & 7);
    int lane   = (int)((tid >> 3) & 63);
    int kt     = (int)((tid >> 9) % KT);
    int ntile  = (int)(tid / (512L * KT));
    int n      = ntile * 16 + (lane & 15);
    int klocal = (lane >> 4) * 8 + j;
    float v;
    if (kt < KTx) v = W[(long)(kt * 32 + klocal) * NG_ + n];
    else          v = Uw[(long)((kt - KTx) * 32 + klocal) * NG_ + n];
    dst[tid] = f2bf(v);
}

// One LSTM timestep for both layers (pipelined): blocks 0..63 -> layer1 step t1,
// blocks 64..127 -> layer2 step t2. Each wave: 16 m-rows x 32 units x 4 gates.
__global__ __launch_bounds__(256) void step_kernel(
    int t1, int t2,
    const unsigned short* __restrict__ xb,     // [B][T][64] bf16
    const unsigned short* __restrict__ B1pk,   // [128][18][64][8]
    const unsigned short* __restrict__ B2pk,   // [128][32][64][8]
    const float* __restrict__ b1,
    const float* __restrict__ b2,
    unsigned short* __restrict__ h1ring,       // 2 * B*U bf16
    unsigned short* __restrict__ h2ring,       // 2 * B*U bf16
    float* __restrict__ c1,                    // B*U fp32
    float* __restrict__ c2)
{
    int blk  = blockIdx.x;
    bool isL2 = blk >= 64;
    int b    = isL2 ? blk - 64 : blk;
    int t    = isL2 ? t2 : t1;
    if (t < 0 || t >= T_) return;

    int mblk = b >> 3;                 // 8 m-blocks of 32 rows
    int ublk = b & 7;                  // 8 unit-blocks of 64 units
    int w    = threadIdx.x >> 6;       // wave 0..3
    int lane = threadIdx.x & 63;
    int q    = lane >> 4;
    int l15  = lane & 15;

    int mbase = mblk * 32 + (w & 1) * 16;
    int usub  = w >> 1;                            // 0..1
    int ubase = ublk * 64 + usub * 32;             // 32 units per wave
    int ntbase = ubase >> 4;                       // unit tile base (of 32)

    const unsigned short* hprev;
    const unsigned short* hin;
    unsigned short* hout;
    float* cbuf;
    const unsigned short* Bpk;
    const float* bias;
    int KT, KTX;
    if (!isL2) {
        hprev = h1ring + (size_t)((t + 1) & 1) * (B_ * U_);
        hout  = h1ring + (size_t)(t & 1) * (B_ * U_);
        hin   = xb;   // unused marker; layer1 x handled specially
        cbuf = c1; Bpk = B1pk; bias = b1; KT = 18; KTX = 2;
    } else {
        hprev = h2ring + (size_t)((t + 1) & 1) * (B_ * U_);
        hout  = h2ring + (size_t)(t & 1) * (B_ * U_);
        hin   = h1ring + (size_t)(t & 1) * (B_ * U_);
        cbuf = c2; Bpk = B2pk; bias = b2; KT = 32; KTX = 16;
    }

    int ktEnd = (t == 0) ? KTX : KT;   // t==0: h_prev = 0, skip recurrent tiles

    floatx4 acc[4][2];
    #pragma unroll
    for (int g = 0; g < 4; ++g)
        #pragma unroll
        for (int s = 0; s < 2; ++s)
            #pragma unroll
            for (int j = 0; j < 4; ++j) acc[g][s][j] = 0.f;

    int mrow = mbase + l15;

    for (int kt = 0; kt < ktEnd; ++kt) {
        const unsigned short* aptr;
        if (!isL2) {
            if (kt < 2) aptr = xb + ((long)mrow * T_ + t) * F_ + kt * 32 + q * 8;
            else        aptr = hprev + (long)mrow * U_ + (kt - 2) * 32 + q * 8;
        } else {
            if (kt < 16) aptr = hin + (long)mrow * U_ + kt * 32 + q * 8;
            else         aptr = hprev + (long)mrow * U_ + (kt - 16) * 32 + q * 8;
        }
        short8 afrag = *(const short8*)aptr;
        #pragma unroll
        for (int g = 0; g < 4; ++g) {
            #pragma unroll
            for (int s = 0; s < 2; ++s) {
                int ntile = g * 32 + ntbase + s;
                const unsigned short* bptr = Bpk + (((long)ntile * KT + kt) * 64 + lane) * 8;
                short8 bfrag = *(const short8*)bptr;
                acc[g][s] = __builtin_amdgcn_mfma_f32_16x16x32_bf16(afrag, bfrag, acc[g][s], 0, 0, 0);
            }
        }
    }

    // Epilogue: gate math in fp32. D layout: col = lane&15, row = (lane>>4)*4 + j.
    #pragma unroll
    for (int s = 0; s < 2; ++s) {
        int u  = ubase + s * 16 + l15;
        float bi = bias[0 * U_ + u];
        float bf = bias[1 * U_ + u];
        float bg = bias[2 * U_ + u];
        float bo = bias[3 * U_ + u];
        #pragma unroll
        for (int j = 0; j < 4; ++j) {
            int m = mbase + q * 4 + j;
            float zi = acc[0][s][j] + bi;
            float zf = acc[1][s][j] + bf;
            float zg = acc[2][s][j] + bg;
            float zo = acc[3][s][j] + bo;
            float si = 1.f / (1.f + __expf(-zi));
            float sf = 1.f / (1.f + __expf(-zf));
            float so = 1.f / (1.f + __expf(-zo));
            float gg = zg > 0.f ? zg : 0.f;
            float cp = (t > 0) ? cbuf[(long)m * U_ + u] : 0.f;
            float cn = sf * cp + si * gg;
            float hr = cn > 0.f ? cn : 0.f;
            float hn = so * hr;
            cbuf[(long)m * U_ + u] = cn;
            hout[(long)m * U_ + u] = f2bf(hn);
        }
    }
}

__global__ void dense_kernel(const unsigned short* __restrict__ h2,
                             const float* __restrict__ Wd,
                             const float* __restrict__ bd,
                             float* __restrict__ out) {
    int b = blockIdx.x;
    int lane = threadIdx.x;                  // 64 lanes
    const unsigned short* hp = h2 + (long)b * U_ + lane * 8;
    float sum = 0.f;
    #pragma unroll
    for (int j = 0; j < 8; ++j) sum += bf2f(hp[j]) * Wd[lane * 8 + j];
    #pragma unroll
    for (int off = 32; off; off >>= 1) sum += __shfl_down(sum, off);
    if (lane == 0) out[b] = 1.f / (1.f + __expf(-(sum + bd[0])));
}

extern "C" void kernel_launch(void* const* d_in, const int* in_sizes, int n_in,
                              void* d_out, int out_size, void* d_ws, size_t ws_size,
                              hipStream_t stream) {
    const float* x  = (const float*)d_in[0];
    const float* W1 = (const float*)d_in[1];
    const float* U1 = (const float*)d_in[2];
    const float* b1 = (const float*)d_in[3];
    const float* W2 = (const float*)d_in[4];
    const float* U2 = (const float*)d_in[5];
    const float* b2 = (const float*)d_in[6];
    const float* Wd = (const float*)d_in[7];
    const float* bd = (const float*)d_in[8];
    float* out = (float*)d_out;

    char* ws = (char*)d_ws;
    size_t off = 0;
    unsigned short* xb   = (unsigned short*)(ws + off); off += (size_t)B_ * T_ * F_ * 2;     // 8.39 MB
    unsigned short* B1pk = (unsigned short*)(ws + off); off += (size_t)128 * 18 * 512 * 2;   // 2.36 MB
    unsigned short* B2pk = (unsigned short*)(ws + off); off += (size_t)128 * 32 * 512 * 2;   // 4.19 MB
    unsigned short* h1r  = (unsigned short*)(ws + off); off += (size_t)2 * B_ * U_ * 2;
    unsigned short* h2r  = (unsigned short*)(ws + off); off += (size_t)2 * B_ * U_ * 2;
    float* c1 = (float*)(ws + off); off += (size_t)B_ * U_ * 4;
    float* c2 = (float*)(ws + off); off += (size_t)B_ * U_ * 4;
    // total ~16.3 MiB of ws

    int n = B_ * T_ * F_;
    cast_x_kernel<<<(n + 255) / 256, 256, 0, stream>>>(x, xb, n);
    {
        long tot1 = 128L * 18 * 512;
        pack_kernel<<<(int)((tot1 + 255) / 256), 256, 0, stream>>>(W1, U1, B1pk, 18, 2);
        long tot2 = 128L * 32 * 512;
        pack_kernel<<<(int)((tot2 + 255) / 256), 256, 0, stream>>>(W2, U2, B2pk, 32, 16);
    }
    // Pipelined recurrence: launch k runs layer1 step k and layer2 step k-1.
    for (int k = 0; k <= T_; ++k) {
        step_kernel<<<128, 256, 0, stream>>>(k, k - 1, xb, B1pk, B2pk,
                                             b1, b2, h1r, h2r, c1, c2);
    }
    dense_kernel<<<B_, 64, 0, stream>>>(h2r + (size_t)((T_ - 1) & 1) * (B_ * U_),
                                        Wd, bd, out);
}